// Round 6
// baseline (292.812 us; speedup 1.0000x reference)
//
#include <hip/hip_runtime.h>
#include <hip/hip_bf16.h>
#include <math.h>

typedef unsigned long long u64;
typedef unsigned char u8;
typedef unsigned short u16;
typedef unsigned int u32;
typedef float fvec4 __attribute__((ext_vector_type(4)));

#define BB 8
#define CC 19
#define HH 512
#define WW 512
#define HWSZ (HH*WW)
#define NIMG 16

// ---------------------------------------------------------------------------
// 1) fused: argmax over channels -> img_p = (u8)(-cls); img_l = floor(lab*255);
//    zero loss accumulator + hysteresis handshake flags.
//    HBM-bound floor: must read all 167 MB of inputs (~25 us at 6.9 TB/s).
// ---------------------------------------------------------------------------
__global__ __launch_bounds__(256) void k_pre(const float* __restrict__ pred,
                                             const float* __restrict__ lab,
                                             u8* __restrict__ img,
                                             u32* __restrict__ flags,
                                             float* __restrict__ out) {
    int idx = blockIdx.x * 256 + threadIdx.x;   // 4 pixels per thread
    if (idx == 0) out[0] = 0.0f;
    if (idx < NIMG) flags[idx] = 0u;            // d_ws is poisoned 0xAA each call
    int p4 = idx * 4;
    int b = p4 / HWSZ;
    int rem = p4 - b * HWSZ;
    const fvec4* base = (const fvec4*)(pred + (size_t)b * CC * HWSZ + rem);
    fvec4 best = __builtin_nontemporal_load(&base[0]);   // read-once stream
    int ix = 0, iy = 0, iz = 0, iw = 0;
    for (int c = 1; c < CC; ++c) {
        fvec4 v = __builtin_nontemporal_load(&base[(size_t)c * (HWSZ / 4)]);
        if (v.x > best.x) { best.x = v.x; ix = c; }
        if (v.y > best.y) { best.y = v.y; iy = c; }
        if (v.z > best.z) { best.z = v.z; iz = c; }
        if (v.w > best.w) { best.w = v.w; iw = c; }
    }
    uchar4 o;
    o.x = (u8)(-ix); o.y = (u8)(-iy); o.z = (u8)(-iz); o.w = (u8)(-iw);
    *(uchar4*)(img + p4) = o;
    float4 v = *(const float4*)(lab + p4);
    uchar4 ol;
    ol.x = (u8)(v.x * 255.0f);
    ol.y = (u8)(v.y * 255.0f);
    ol.z = (u8)(v.z * 255.0f);
    ol.w = (u8)(v.w * 255.0f);
    *(uchar4*)(img + (size_t)BB * HWSZ + p4) = ol;
}

// ---------------------------------------------------------------------------
// Sobel for 8 pixels of one row (edge-replicate padding). mag <= 2040.
// ---------------------------------------------------------------------------
__device__ __forceinline__ void sobel8(const u8* __restrict__ base, int yy, int x0,
                                       int mag8[8], u32* dirpack) {
    int r0 = (yy == 0) ? 0 : yy - 1;
    int r2 = (yy == 511) ? 511 : yy + 1;
    const u8* rps[3] = { base + r0 * WW, base + yy * WW, base + r2 * WW };
    int bb[3][10];
#pragma unroll
    for (int r = 0; r < 3; ++r) {
        u64 m = *(const u64*)(rps[r] + x0);
        bb[r][0] = (x0 == 0) ? rps[r][0] : rps[r][x0 - 1];
#pragma unroll
        for (int i = 0; i < 8; ++i) bb[r][i + 1] = (int)((m >> (8 * i)) & 0xFF);
        bb[r][9] = (x0 == 504) ? rps[r][511] : rps[r][x0 + 8];
    }
    u32 dp = 0;
#pragma unroll
    for (int i = 0; i < 8; ++i) {
        int a00 = bb[0][i], a01 = bb[0][i + 1], a02 = bb[0][i + 2];
        int a10 = bb[1][i],                     a12 = bb[1][i + 2];
        int a20 = bb[2][i], a21 = bb[2][i + 1], a22 = bb[2][i + 2];
        int gx = (a02 + 2 * a12 + a22) - (a00 + 2 * a10 + a20);
        int gy = (a20 + 2 * a21 + a22) - (a00 + 2 * a01 + a02);
        int ax = gx < 0 ? -gx : gx;
        int ay = gy < 0 ? -gy : gy;
        mag8[i] = ax + ay;
        if (dirpack) {
            float fax = (float)ax, fay = (float)ay;
            u32 dir;
            if (fay < 0.41421356237309515f * fax) dir = 0;       // <22.5 or >=157.5
            else if (fay >= 2.414213562373095f * fax) dir = 2;   // [67.5,112.5)
            else dir = ((gx ^ gy) >= 0) ? 1u : 3u;               // 45 : 135
            dp |= dir << (2 * i);
        }
    }
    if (dirpack) *dirpack = dp;
}

// ---------------------------------------------------------------------------
// 2) fused Sobel + NMS + double threshold -> bit-packed weak/strong.
//    Block = 4-row x 512-col strip; 6 mag rows staged in LDS.
// ---------------------------------------------------------------------------
__global__ __launch_bounds__(256) void k_gradnms(const u8* __restrict__ imgs,
                                                 u64* __restrict__ weak,
                                                 u64* __restrict__ strong) {
    __shared__ u16 smag[6][514];         // [row y0-1 .. y0+4][1 + x], cols 0,513 = 0
    __shared__ alignas(8) u8 wb[4][64];
    __shared__ alignas(8) u8 sb[4][64];
    int im = blockIdx.x >> 7;            // 128 strips per image
    int y0 = (blockIdx.x & 127) * 4;
    int r    = threadIdx.x >> 6;         // wave index = row in strip (uniform branches)
    int lane = threadIdx.x & 63;
    int x0 = lane * 8;
    const u8* base = imgs + (size_t)im * HWSZ;

    if (threadIdx.x < 6) { smag[threadIdx.x][0] = 0; smag[threadIdx.x][513] = 0; }

    int y = y0 + r;
    int mag8[8]; u32 dp;
    sobel8(base, y, x0, mag8, &dp);
#pragma unroll
    for (int i = 0; i < 8; ++i) smag[r + 1][1 + x0 + i] = (u16)mag8[i];

    if (r == 0) {
        if (y0 > 0) {
            int m2[8]; sobel8(base, y0 - 1, x0, m2, nullptr);
#pragma unroll
            for (int i = 0; i < 8; ++i) smag[0][1 + x0 + i] = (u16)m2[i];
        } else {
#pragma unroll
            for (int i = 0; i < 8; ++i) smag[0][1 + x0 + i] = 0;
        }
    } else if (r == 3) {
        if (y0 + 4 < 512) {
            int m2[8]; sobel8(base, y0 + 4, x0, m2, nullptr);
#pragma unroll
            for (int i = 0; i < 8; ++i) smag[5][1 + x0 + i] = (u16)m2[i];
        } else {
#pragma unroll
            for (int i = 0; i < 8; ++i) smag[5][1 + x0 + i] = 0;
        }
    }
    __syncthreads();

    int wbits = 0, sbits = 0;
#pragma unroll
    for (int i = 0; i < 8; ++i) {
        int x = x0 + i;
        int mag = mag8[i];
        int dir = (int)((dp >> (2 * i)) & 3u);
        int n1, n2;
        switch (dir) {
            case 0:  n1 = smag[r + 1][x];     n2 = smag[r + 1][x + 2]; break;
            case 1:  n1 = smag[r][x + 2];     n2 = smag[r + 2][x];     break;
            case 2:  n1 = smag[r][x + 1];     n2 = smag[r + 2][x + 1]; break;
            default: n1 = smag[r][x];         n2 = smag[r + 2][x + 2]; break;
        }
        int keep = (mag >= n1) & (mag >= n2);
        wbits |= (keep & (mag > 100)) << i;
        sbits |= (keep & (mag > 200)) << i;
    }
    wb[r][lane] = (u8)wbits;
    sb[r][lane] = (u8)sbits;
    __syncthreads();

    if (threadIdx.x < 32) {
        int rr = threadIdx.x >> 3;       // row in strip
        int w  = threadIdx.x & 7;        // u64 word in row
        u64 W = *(const u64*)&wb[rr][w * 8];   // little-endian byte k -> bits 8k
        u64 S = *(const u64*)&sb[rr][w * 8];
        size_t o = ((size_t)im * HH + (y0 + rr)) * 8 + w;
        weak[o] = W;
        strong[o] = S;
    }
}

// ---------------------------------------------------------------------------
// 3) hysteresis to least fixed point + fused loss.
//    One block/image (16 blocks <= 256 CUs: trivially co-resident, so the
//    device-scope flag handshake cannot deadlock). After convergence each
//    block publishes edges; blocks 0..7 wait for partner im+8 and compute the
//    pair's loss columns.
//    Loss: per column (b,x): K = popcount(ep col), Z = 512 + (e-1)*K,
//    col = E*log(Z) - O; out = mean over 4096 columns.
// ---------------------------------------------------------------------------
__global__ __launch_bounds__(512) void k_hyst(const u64* __restrict__ weakg,
                                              const u64* __restrict__ strongg,
                                              u64* __restrict__ edges,
                                              u32* __restrict__ flags,
                                              float* __restrict__ out) {
    __shared__ u32 hlo[8][512];   // lane stride 4B -> bank = y%32 -> conflict-free
    __shared__ u32 hhi[8][512];
    __shared__ int bflags[2];
    int y = threadIdx.x;
    int im = blockIdx.x;
    size_t base = ((size_t)im * HH + y) * 8;
    u64 wk[8], s[8];
#pragma unroll
    for (int j = 0; j < 8; ++j) {
        wk[j] = weakg[base + j];
        s[j] = strongg[base + j];     // strong subset of weak
    }
    for (int it = 0; it < 256; ++it) {
        u64 diff = 0;
        // horizontal fill rightward (bit-carry run fill)
        u64 c = 0;
#pragma unroll
        for (int j = 0; j < 8; ++j) {
            u64 a = s[j], w = wk[j];
            u64 t1 = a + w;       u64 c1 = (u64)(t1 < a);
            u64 t2 = t1 + c;      u64 c2 = (u64)(t2 < t1);
            u64 ns = a | ((t2 ^ w) & w);
            diff |= ns ^ a;
            s[j] = ns;
            c = c1 | c2;
        }
        // horizontal fill leftward via bit reversal
        c = 0;
#pragma unroll
        for (int j = 7; j >= 0; --j) {
            u64 a = __builtin_bitreverse64(s[j]);
            u64 w = __builtin_bitreverse64(wk[j]);
            u64 t1 = a + w;       u64 c1 = (u64)(t1 < a);
            u64 t2 = t1 + c;      u64 c2 = (u64)(t2 < t1);
            u64 nsr = a | ((t2 ^ w) & w);
            u64 ns = __builtin_bitreverse64(nsr);
            diff |= ns ^ s[j];
            s[j] = ns;
            c = c1 | c2;
        }
        // horizontally dilated row -> LDS
        u64 hh[8];
#pragma unroll
        for (int j = 0; j < 8; ++j) hh[j] = s[j] | (s[j] << 1) | (s[j] >> 1);
#pragma unroll
        for (int j = 1; j < 8; ++j) hh[j] |= s[j - 1] >> 63;
#pragma unroll
        for (int j = 0; j < 7; ++j) hh[j] |= s[j + 1] << 63;
#pragma unroll
        for (int j = 0; j < 8; ++j) {
            hlo[j][y] = (u32)hh[j];
            hhi[j][y] = (u32)(hh[j] >> 32);
        }
        if (y == 0 && it == 0) bflags[0] = 0;
        __syncthreads();
        if (y == 0) bflags[(it + 1) & 1] = 0;
        // vertical/diagonal hop
#pragma unroll
        for (int j = 0; j < 8; ++j) {
            u64 up = (y > 0)   ? ((u64)hlo[j][y - 1] | ((u64)hhi[j][y - 1] << 32)) : 0ull;
            u64 dn = (y < 511) ? ((u64)hlo[j][y + 1] | ((u64)hhi[j][y + 1] << 32)) : 0ull;
            u64 t = wk[j] & (up | dn) & ~s[j];
            diff |= t;
            s[j] |= t;
        }
        if (diff) bflags[it & 1] = 1;
        __syncthreads();
        if (!bflags[it & 1]) break;
    }
    // publish converged edges (release: store -> per-thread fence -> sync -> flag)
#pragma unroll
    for (int j = 0; j < 8; ++j) edges[base + j] = s[j];
    __threadfence();
    __syncthreads();
    if (threadIdx.x == 0) atomicExch(&flags[im], 1u);

    // blocks 0..7: wait for partner image, then compute the pair's loss
    if (im < 8) {
        if (threadIdx.x == 0) {
            while (atomicAdd(&flags[im + 8], 0u) == 0u) { __builtin_amdgcn_s_sleep(8); }
        }
        __syncthreads();
        __threadfence();   // acquire: invalidate caches before reading partner edges
        int g = threadIdx.x >> 6;      // wave -> word column
        int l = threadIdx.x & 63;      // lane -> bit (x = 64g + l)
        const u64* ep = edges + (size_t)im * HH * 8 + g;
        const u64* el = edges + (size_t)(im + 8) * HH * 8 + g;
        int K = 0, E = 0, O = 0;
        for (int yy = 0; yy < 512; ++yy) {
            u64 wp = ep[(size_t)yy * 8];   // broadcast load within wave
            u64 wl = el[(size_t)yy * 8];
            int bp = (int)((wp >> l) & 1ull);
            int bl = (int)((wl >> l) & 1ull);
            K += bp; E += bl; O += (bp & bl);
        }
        float logZ = logf(512.0f + 1.7182818284590452f * (float)K);
        float v = ((float)E * logZ - (float)O) * (1.0f / 4096.0f);
#pragma unroll
        for (int o = 32; o > 0; o >>= 1) v += __shfl_down(v, o, 64);
        if (l == 0) atomicAdd(out, v);
    }
}

// ---------------------------------------------------------------------------
extern "C" void kernel_launch(void* const* d_in, const int* in_sizes, int n_in,
                              void* d_out, int out_size, void* d_ws, size_t ws_size,
                              hipStream_t stream) {
    const float* pred = (const float*)d_in[0];
    const float* labels = (const float*)d_in[1];
    float* out = (float*)d_out;

    // workspace layout (bytes)
    u8*  imgs   = (u8*)d_ws;                                        // 16*HWSZ = 4 MiB
    u64* weak   = (u64*)((char*)d_ws + (size_t)NIMG * HWSZ);        // 512 KiB
    u64* strong = (u64*)((char*)weak + (size_t)NIMG * HH * 8 * 8);  // 512 KiB
    u64* edges  = (u64*)((char*)strong + (size_t)NIMG * HH * 8 * 8);// 512 KiB
    u32* flags  = (u32*)((char*)edges + (size_t)NIMG * HH * 8 * 8); // 64 B

    hipLaunchKernelGGL(k_pre, dim3(BB * HWSZ / 4 / 256), dim3(256), 0, stream,
                       pred, labels, imgs, flags, out);
    hipLaunchKernelGGL(k_gradnms, dim3(NIMG * 128), dim3(256), 0, stream,
                       imgs, weak, strong);
    hipLaunchKernelGGL(k_hyst, dim3(NIMG), dim3(512), 0, stream,
                       weak, strong, edges, flags, out);
}

// Round 7
// 250.541 us; speedup vs baseline: 1.1687x; 1.1687x over previous
//
#include <hip/hip_runtime.h>
#include <hip/hip_bf16.h>
#include <math.h>

typedef unsigned long long u64;
typedef unsigned char u8;
typedef unsigned short u16;
typedef unsigned int u32;

#define BB 8
#define CC 19
#define HH 512
#define WW 512
#define HWSZ (HH*WW)
#define NIMG 16

// ---------------------------------------------------------------------------
// 1) fused: argmax over channels -> img_p = (u8)(-cls); img_l = floor(lab*255);
//    zero the loss accumulator.  HBM-bound: must read all 168 MB of inputs.
// ---------------------------------------------------------------------------
__global__ __launch_bounds__(256) void k_pre(const float* __restrict__ pred,
                                             const float* __restrict__ lab,
                                             u8* __restrict__ img,
                                             float* __restrict__ out) {
    int idx = blockIdx.x * 256 + threadIdx.x;   // 4 pixels per thread
    if (idx == 0) out[0] = 0.0f;
    int p4 = idx * 4;
    int b = p4 / HWSZ;
    int rem = p4 - b * HWSZ;
    const float4* base = (const float4*)(pred + (size_t)b * CC * HWSZ + rem);
    float4 best = base[0];
    int ix = 0, iy = 0, iz = 0, iw = 0;
    for (int c = 1; c < CC; ++c) {
        float4 v = base[(size_t)c * (HWSZ / 4)];
        if (v.x > best.x) { best.x = v.x; ix = c; }
        if (v.y > best.y) { best.y = v.y; iy = c; }
        if (v.z > best.z) { best.z = v.z; iz = c; }
        if (v.w > best.w) { best.w = v.w; iw = c; }
    }
    uchar4 o;
    o.x = (u8)(-ix); o.y = (u8)(-iy); o.z = (u8)(-iz); o.w = (u8)(-iw);
    *(uchar4*)(img + p4) = o;
    float4 v = *(const float4*)(lab + p4);
    uchar4 ol;
    ol.x = (u8)(v.x * 255.0f);
    ol.y = (u8)(v.y * 255.0f);
    ol.z = (u8)(v.z * 255.0f);
    ol.w = (u8)(v.w * 255.0f);
    *(uchar4*)(img + (size_t)BB * HWSZ + p4) = ol;
}

// ---------------------------------------------------------------------------
// Sobel for 8 pixels of one row (edge-replicate padding). mag <= 2040.
// ---------------------------------------------------------------------------
__device__ __forceinline__ void sobel8(const u8* __restrict__ base, int yy, int x0,
                                       int mag8[8], u32* dirpack) {
    int r0 = (yy == 0) ? 0 : yy - 1;
    int r2 = (yy == 511) ? 511 : yy + 1;
    const u8* rps[3] = { base + r0 * WW, base + yy * WW, base + r2 * WW };
    int bb[3][10];
#pragma unroll
    for (int r = 0; r < 3; ++r) {
        u64 m = *(const u64*)(rps[r] + x0);
        bb[r][0] = (x0 == 0) ? rps[r][0] : rps[r][x0 - 1];
#pragma unroll
        for (int i = 0; i < 8; ++i) bb[r][i + 1] = (int)((m >> (8 * i)) & 0xFF);
        bb[r][9] = (x0 == 504) ? rps[r][511] : rps[r][x0 + 8];
    }
    u32 dp = 0;
#pragma unroll
    for (int i = 0; i < 8; ++i) {
        int a00 = bb[0][i], a01 = bb[0][i + 1], a02 = bb[0][i + 2];
        int a10 = bb[1][i],                     a12 = bb[1][i + 2];
        int a20 = bb[2][i], a21 = bb[2][i + 1], a22 = bb[2][i + 2];
        int gx = (a02 + 2 * a12 + a22) - (a00 + 2 * a10 + a20);
        int gy = (a20 + 2 * a21 + a22) - (a00 + 2 * a01 + a02);
        int ax = gx < 0 ? -gx : gx;
        int ay = gy < 0 ? -gy : gy;
        mag8[i] = ax + ay;
        if (dirpack) {
            float fax = (float)ax, fay = (float)ay;
            u32 dir;
            if (fay < 0.41421356237309515f * fax) dir = 0;       // <22.5 or >=157.5
            else if (fay >= 2.414213562373095f * fax) dir = 2;   // [67.5,112.5)
            else dir = ((gx ^ gy) >= 0) ? 1u : 3u;               // 45 : 135
            dp |= dir << (2 * i);
        }
    }
    if (dirpack) *dirpack = dp;
}

// ---------------------------------------------------------------------------
// 2) fused Sobel + NMS + double threshold -> bit-packed weak/strong.
//    Block = 4-row x 512-col strip; 6 mag rows staged in LDS (zeroed edge
//    cols emulate the reference's zero-pad of mag). 1.5x Sobel redundancy
//    replaces an 8 MB magdir global round-trip.
// ---------------------------------------------------------------------------
__global__ __launch_bounds__(256) void k_gradnms(const u8* __restrict__ imgs,
                                                 u64* __restrict__ weak,
                                                 u64* __restrict__ strong) {
    __shared__ u16 smag[6][514];         // [row y0-1 .. y0+4][1 + x], cols 0,513 = 0
    __shared__ alignas(8) u8 wb[4][64];
    __shared__ alignas(8) u8 sb[4][64];
    int im = blockIdx.x >> 7;            // 128 strips per image
    int y0 = (blockIdx.x & 127) * 4;
    int r    = threadIdx.x >> 6;         // wave index = row in strip (uniform branches)
    int lane = threadIdx.x & 63;
    int x0 = lane * 8;
    const u8* base = imgs + (size_t)im * HWSZ;

    if (threadIdx.x < 6) { smag[threadIdx.x][0] = 0; smag[threadIdx.x][513] = 0; }

    int y = y0 + r;
    int mag8[8]; u32 dp;
    sobel8(base, y, x0, mag8, &dp);
#pragma unroll
    for (int i = 0; i < 8; ++i) smag[r + 1][1 + x0 + i] = (u16)mag8[i];

    if (r == 0) {
        if (y0 > 0) {
            int m2[8]; sobel8(base, y0 - 1, x0, m2, nullptr);
#pragma unroll
            for (int i = 0; i < 8; ++i) smag[0][1 + x0 + i] = (u16)m2[i];
        } else {
#pragma unroll
            for (int i = 0; i < 8; ++i) smag[0][1 + x0 + i] = 0;
        }
    } else if (r == 3) {
        if (y0 + 4 < 512) {
            int m2[8]; sobel8(base, y0 + 4, x0, m2, nullptr);
#pragma unroll
            for (int i = 0; i < 8; ++i) smag[5][1 + x0 + i] = (u16)m2[i];
        } else {
#pragma unroll
            for (int i = 0; i < 8; ++i) smag[5][1 + x0 + i] = 0;
        }
    }
    __syncthreads();

    int wbits = 0, sbits = 0;
#pragma unroll
    for (int i = 0; i < 8; ++i) {
        int x = x0 + i;
        int mag = mag8[i];
        int dir = (int)((dp >> (2 * i)) & 3u);
        int n1, n2;
        switch (dir) {
            case 0:  n1 = smag[r + 1][x];     n2 = smag[r + 1][x + 2]; break;
            case 1:  n1 = smag[r][x + 2];     n2 = smag[r + 2][x];     break;
            case 2:  n1 = smag[r][x + 1];     n2 = smag[r + 2][x + 1]; break;
            default: n1 = smag[r][x];         n2 = smag[r + 2][x + 2]; break;
        }
        int keep = (mag >= n1) & (mag >= n2);
        wbits |= (keep & (mag > 100)) << i;
        sbits |= (keep & (mag > 200)) << i;
    }
    wb[r][lane] = (u8)wbits;
    sb[r][lane] = (u8)sbits;
    __syncthreads();

    if (threadIdx.x < 32) {
        int rr = threadIdx.x >> 3;       // row in strip
        int w  = threadIdx.x & 7;        // u64 word in row
        u64 W = *(const u64*)&wb[rr][w * 8];   // little-endian byte k -> bits 8k
        u64 S = *(const u64*)&sb[rr][w * 8];
        size_t o = ((size_t)im * HH + (y0 + rr)) * 8 + w;
        weak[o] = W;
        strong[o] = S;
    }
}

// ---------------------------------------------------------------------------
// 3) hysteresis to least fixed point. One block/image, one row (8 u64)/thread.
//    Horizontal run-fill (bit-carry) + vertical Jacobi hop through
//    conflict-free split-u32 LDS. Monotone chaotic iteration => same fixed
//    point as the reference's (converged) 256-cap Jacobi.
// ---------------------------------------------------------------------------
__global__ __launch_bounds__(512) void k_hyst(const u64* __restrict__ weakg,
                                              const u64* __restrict__ strongg,
                                              u64* __restrict__ edges) {
    __shared__ u32 hlo[8][512];   // lane stride 4B -> bank = y%32 -> conflict-free
    __shared__ u32 hhi[8][512];
    __shared__ int flags[2];
    int y = threadIdx.x;
    int im = blockIdx.x;
    size_t base = ((size_t)im * HH + y) * 8;
    u64 wk[8], s[8];
#pragma unroll
    for (int j = 0; j < 8; ++j) {
        wk[j] = weakg[base + j];
        s[j] = strongg[base + j];     // strong subset of weak
    }
    for (int it = 0; it < 256; ++it) {
        u64 diff = 0;
        // horizontal fill rightward (bit-carry run fill)
        u64 c = 0;
#pragma unroll
        for (int j = 0; j < 8; ++j) {
            u64 a = s[j], w = wk[j];
            u64 t1 = a + w;       u64 c1 = (u64)(t1 < a);
            u64 t2 = t1 + c;      u64 c2 = (u64)(t2 < t1);
            u64 ns = a | ((t2 ^ w) & w);
            diff |= ns ^ a;
            s[j] = ns;
            c = c1 | c2;
        }
        // horizontal fill leftward via bit reversal
        c = 0;
#pragma unroll
        for (int j = 7; j >= 0; --j) {
            u64 a = __builtin_bitreverse64(s[j]);
            u64 w = __builtin_bitreverse64(wk[j]);
            u64 t1 = a + w;       u64 c1 = (u64)(t1 < a);
            u64 t2 = t1 + c;      u64 c2 = (u64)(t2 < t1);
            u64 nsr = a | ((t2 ^ w) & w);
            u64 ns = __builtin_bitreverse64(nsr);
            diff |= ns ^ s[j];
            s[j] = ns;
            c = c1 | c2;
        }
        // horizontally dilated row -> LDS
        u64 hh[8];
#pragma unroll
        for (int j = 0; j < 8; ++j) hh[j] = s[j] | (s[j] << 1) | (s[j] >> 1);
#pragma unroll
        for (int j = 1; j < 8; ++j) hh[j] |= s[j - 1] >> 63;
#pragma unroll
        for (int j = 0; j < 7; ++j) hh[j] |= s[j + 1] << 63;
#pragma unroll
        for (int j = 0; j < 8; ++j) {
            hlo[j][y] = (u32)hh[j];
            hhi[j][y] = (u32)(hh[j] >> 32);
        }
        if (y == 0 && it == 0) flags[0] = 0;
        __syncthreads();
        if (y == 0) flags[(it + 1) & 1] = 0;
        // vertical/diagonal hop
#pragma unroll
        for (int j = 0; j < 8; ++j) {
            u64 up = (y > 0)   ? ((u64)hlo[j][y - 1] | ((u64)hhi[j][y - 1] << 32)) : 0ull;
            u64 dn = (y < 511) ? ((u64)hlo[j][y + 1] | ((u64)hhi[j][y + 1] << 32)) : 0ull;
            u64 t = wk[j] & (up | dn) & ~s[j];
            diff |= t;
            s[j] |= t;
        }
        if (diff) flags[it & 1] = 1;
        __syncthreads();
        if (!flags[it & 1]) break;
    }
#pragma unroll
    for (int j = 0; j < 8; ++j) edges[base + j] = s[j];
}

// ---------------------------------------------------------------------------
// 4) loss. Per column (b,w): k = popcount(ep col), Z = 512 + (e-1)*k,
//    col = elsum*log(Z) - overlap; out = mean over 4096 columns.
//    64 blocks x 4 waves: enough TLP to hide L2-warm load latency.
// ---------------------------------------------------------------------------
__global__ __launch_bounds__(256) void k_loss(const u64* __restrict__ edges,
                                              float* __restrict__ out) {
    int b = blockIdx.x >> 3;        // image pair index
    int j = blockIdx.x & 7;         // word column
    int wave = threadIdx.x >> 6;
    int lane = threadIdx.x & 63;
    const u64* ep = edges + ((size_t)b * HH) * 8 + j;
    const u64* el = edges + ((size_t)(b + 8) * HH) * 8 + j;
    int k = 0, es = 0, ov = 0;
    int y0 = wave * 128;
    for (int y = y0; y < y0 + 128; ++y) {
        u64 wp = ep[(size_t)y * 8];
        u64 wl = el[(size_t)y * 8];
        int bp = (int)((wp >> lane) & 1ull);
        int bl = (int)((wl >> lane) & 1ull);
        k += bp; es += bl; ov += (bp & bl);
    }
    __shared__ int red[3][4][64];
    red[0][wave][lane] = k;
    red[1][wave][lane] = es;
    red[2][wave][lane] = ov;
    __syncthreads();
    if (threadIdx.x < 64) {
        int l = threadIdx.x;
        int K = red[0][0][l] + red[0][1][l] + red[0][2][l] + red[0][3][l];
        int E = red[1][0][l] + red[1][1][l] + red[1][2][l] + red[1][3][l];
        int O = red[2][0][l] + red[2][1][l] + red[2][2][l] + red[2][3][l];
        float logZ = logf(512.0f + 1.7182818284590452f * (float)K);
        float v = ((float)E * logZ - (float)O) * (1.0f / 4096.0f);
#pragma unroll
        for (int o = 32; o > 0; o >>= 1) v += __shfl_down(v, o, 64);
        if (l == 0) atomicAdd(out, v);
    }
}

// ---------------------------------------------------------------------------
extern "C" void kernel_launch(void* const* d_in, const int* in_sizes, int n_in,
                              void* d_out, int out_size, void* d_ws, size_t ws_size,
                              hipStream_t stream) {
    const float* pred = (const float*)d_in[0];
    const float* labels = (const float*)d_in[1];
    float* out = (float*)d_out;

    // workspace layout (bytes)
    u8*  imgs   = (u8*)d_ws;                                        // 16*HWSZ = 4 MiB
    u64* weak   = (u64*)((char*)d_ws + (size_t)NIMG * HWSZ);        // 512 KiB
    u64* strong = (u64*)((char*)weak + (size_t)NIMG * HH * 8 * 8);  // 512 KiB
    u64* edges  = (u64*)((char*)strong + (size_t)NIMG * HH * 8 * 8);// 512 KiB

    hipLaunchKernelGGL(k_pre, dim3(BB * HWSZ / 4 / 256), dim3(256), 0, stream,
                       pred, labels, imgs, out);
    hipLaunchKernelGGL(k_gradnms, dim3(NIMG * 128), dim3(256), 0, stream,
                       imgs, weak, strong);
    hipLaunchKernelGGL(k_hyst, dim3(NIMG), dim3(512), 0, stream,
                       weak, strong, edges);
    hipLaunchKernelGGL(k_loss, dim3(64), dim3(256), 0, stream, edges, out);
}